// Round 1
// baseline (223.368 us; speedup 1.0000x reference)
//
#include <hip/hip_runtime.h>
#include <cstdint>
#include <cstddef>

// ---------------------------------------------------------------
// SparseAttention: B=2 L=4096 D=1024 H=16 HD=64 BS=64 NB=64 MAXB=11
// ---------------------------------------------------------------

#define B_   2
#define L_   4096
#define D_   1024
#define H_   16
#define HD_  64
#define NBLK 64
#define MAXB 11

typedef __attribute__((ext_vector_type(8))) short short8;
typedef __attribute__((ext_vector_type(4))) float f32x4;

#define MFMA16(a, b, c) __builtin_amdgcn_mfma_f32_16x16x32_bf16((a), (b), (c), 0, 0, 0)

__device__ __forceinline__ ushort f2bf(float f) {
  uint32_t u = __float_as_uint(f);
  u += 0x7FFFu + ((u >> 16) & 1u);   // RTN-even
  return (ushort)(u >> 16);
}

__device__ __forceinline__ void gload_lds16(const ushort* g, ushort* l) {
  __builtin_amdgcn_global_load_lds((const __attribute__((address_space(1))) void*)g,
                                   (__attribute__((address_space(3))) void*)l, 16, 0, 0);
}

// ---------------- f32 -> bf16 conversion (x4 vectorized) ----------------
__global__ __launch_bounds__(256) void cvt_kernel(const float* __restrict__ src,
                                                  ushort* __restrict__ dst, int n4) {
  int i = blockIdx.x * 256 + threadIdx.x;
  if (i >= n4) return;
  const float4 v = reinterpret_cast<const float4*>(src)[i];
  ushort4 o;
  o.x = f2bf(v.x); o.y = f2bf(v.y); o.z = f2bf(v.z); o.w = f2bf(v.w);
  reinterpret_cast<ushort4*>(dst)[i] = o;
}

// ---------------- shared GEMM mainloop: C = A * B^T ----------------
// A: [M][K] bf16 row-major, Bm: [N][K] bf16 row-major, K == 1024 here.
// 128x128 tile, BK=64, 256 threads (4 waves, 2x2 of 64x64), m97 structure.
#define BM 128
#define BN 128
#define BK 64

__device__ __forceinline__ void gemm_tile(const ushort* __restrict__ A,
                                          const ushort* __restrict__ Bm,
                                          int K, int m0, int n0,
                                          ushort* As, ushort* Bs,
                                          f32x4 acc[4][4]) {
  const int tid  = threadIdx.x;
  const int w    = tid >> 6;
  const int lane = tid & 63;
  const int g    = lane >> 4;
  const int c    = lane & 15;
  const int wr0  = (w >> 1) * 64;
  const int wc0  = (w & 1) * 64;
  const int fbase = w * 1024 + lane * 16;   // flat byte offset within one 4KB pass

  for (int kt = 0; kt < K; kt += BK) {
    __syncthreads();   // previous iteration's readers done before overwrite
    #pragma unroll
    for (int q = 0; q < 4; ++q) {
      int fb  = q * 4096 + fbase;
      int row = fb >> 7;            // 128 B per LDS row (64 bf16)
      int col = (fb & 127) >> 1;
      gload_lds16(A  + (size_t)(m0 + row) * K + kt + col, As + q * 2048 + w * 512);
      gload_lds16(Bm + (size_t)(n0 + row) * K + kt + col, Bs + q * 2048 + w * 512);
    }
    __syncthreads();   // compiler emits vmcnt(0) drain here
    #pragma unroll
    for (int kc = 0; kc < 2; ++kc) {
      short8 af[4], bfr[4];
      const int kk = kc * 32 + g * 8;
      #pragma unroll
      for (int mi = 0; mi < 4; ++mi)
        af[mi] = *(const short8*)(As + (wr0 + mi * 16 + c) * 64 + kk);
      #pragma unroll
      for (int ni = 0; ni < 4; ++ni)
        bfr[ni] = *(const short8*)(Bs + (wc0 + ni * 16 + c) * 64 + kk);
      #pragma unroll
      for (int mi = 0; mi < 4; ++mi)
        #pragma unroll
        for (int ni = 0; ni < 4; ++ni)
          acc[mi][ni] = MFMA16(af[mi], bfr[ni], acc[mi][ni]);
    }
  }
}

// ---------------- GEMM1: QKV projection with scatter epilogue ----------------
// C[m][n]: n in [0,3072): part = n>>10 (0:Q 1:K 2:V), h=(n>>6)&15, hd=n&63
// Q pre-scaled by 0.125 (= 1/sqrt(64), exact). Layout [B,H,L,HD] bf16.
__global__ __launch_bounds__(256) void gemm_qkv(const ushort* __restrict__ Xb,
                                                const ushort* __restrict__ W,
                                                ushort* __restrict__ Qb,
                                                ushort* __restrict__ Kb,
                                                ushort* __restrict__ Vb) {
  __shared__ ushort As[BM * BK];
  __shared__ ushort Bs[BN * BK];
  const int nbn = 3072 / BN;   // 24
  const int bm = blockIdx.x / nbn, bn = blockIdx.x % nbn;
  const int m0 = bm * BM, n0 = bn * BN;
  f32x4 acc[4][4] = {};
  gemm_tile(Xb, W, 1024, m0, n0, As, Bs, acc);

  const int tid = threadIdx.x;
  const int w = tid >> 6, lane = tid & 63;
  const int g = lane >> 4, c = lane & 15;
  const int wr0 = (w >> 1) * 64, wc0 = (w & 1) * 64;
  #pragma unroll
  for (int mi = 0; mi < 4; ++mi) {
    #pragma unroll
    for (int ni = 0; ni < 4; ++ni) {
      const int n = n0 + wc0 + ni * 16 + c;
      const int part = n >> 10;
      const int h = (n >> 6) & 15;
      const int hd = n & 63;
      #pragma unroll
      for (int r = 0; r < 4; ++r) {
        const int m = m0 + wr0 + mi * 16 + g * 4 + r;
        const int b = m >> 12;
        const int lp = m & 4095;
        const size_t off = ((size_t)((b << 4) + h) * 4096 + lp) * 64 + hd;
        const float v = acc[mi][ni][r];
        if (part == 0)      Qb[off] = f2bf(v * 0.125f);
        else if (part == 1) Kb[off] = f2bf(v);
        else                Vb[off] = f2bf(v);
      }
    }
  }
}

// ---------------- V transpose: [B,H,L,64] -> [B,H,64,L] ----------------
__global__ __launch_bounds__(256) void transpose_v(const ushort* __restrict__ V,
                                                   ushort* __restrict__ Vt) {
  __shared__ ushort t[64][72];
  const int bid = blockIdx.x;
  const int bh = bid >> 6;      // b*16+h
  const int blk = bid & 63;
  const int tid = threadIdx.x;
  const int row = tid >> 2;
  const int cg = (tid & 3) * 16;
  const ushort* src = V + ((size_t)bh * 4096 + blk * 64 + row) * 64 + cg;
  *(short8*)&t[row][cg]     = *(const short8*)src;
  *(short8*)&t[row][cg + 8] = *(const short8*)(src + 8);
  __syncthreads();
  short8 o0, o1;
  #pragma unroll
  for (int i = 0; i < 8; ++i) {
    o0[i] = (short)t[cg + i][row];
    o1[i] = (short)t[cg + 8 + i][row];
  }
  ushort* dst = Vt + ((size_t)bh * 64 + row) * 4096 + blk * 64 + cg;
  *(short8*)dst       = o0;
  *(short8*)(dst + 8) = o1;
}

// ---------------- block-sparse flash attention ----------------
// One block per (b,h,qb). 4 waves x 16 Q-rows. Online softmax across MAXB blocks.
__global__ __launch_bounds__(256) void attn_kernel(const ushort* __restrict__ Qb,
                                                   const ushort* __restrict__ Kb,
                                                   const ushort* __restrict__ Vt,
                                                   const int* __restrict__ bidx,
                                                   const float* __restrict__ slopes,
                                                   ushort* __restrict__ X2) {
  __shared__ ushort Ks[64][72];       // K tile [key][d], also Q tile at start
  __shared__ ushort Vs[64][72];       // Vt tile [d][key]
  __shared__ ushort Ps[4][16][72];    // per-wave P tile [qrow][key]

  const int bid = blockIdx.x;
  const int qb = bid & 63;
  const int h  = (bid >> 6) & 15;
  const int b  = bid >> 10;
  const int bh = b * 16 + h;
  const int tid = threadIdx.x;
  const int w = tid >> 6, lane = tid & 63;
  const int g = lane >> 4, c = lane & 15;
  const int i0 = w * 16;              // wave's first Q row within tile
  const float slope = slopes[h];

  // stage Q tile (into Ks), pull per-wave Q fragments to registers
  {
    const int row = tid >> 2;
    const int cg = (tid & 3) * 16;
    const ushort* src = Qb + ((size_t)bh * 4096 + qb * 64 + row) * 64 + cg;
    *(short8*)&Ks[row][cg]     = *(const short8*)src;
    *(short8*)&Ks[row][cg + 8] = *(const short8*)(src + 8);
  }
  __syncthreads();
  short8 qf[2];
  qf[0] = *(const short8*)&Ks[i0 + c][g * 8];
  qf[1] = *(const short8*)&Ks[i0 + c][32 + g * 8];

  f32x4 accO[4] = {};                 // 4 d-tiles of 16x16
  float mrun[4] = {-3e38f, -3e38f, -3e38f, -3e38f};
  float lrun[4] = {0.f, 0.f, 0.f, 0.f};

  for (int m = 0; m < MAXB; ++m) {
    const int kb = bidx[qb * MAXB + m];
    if (kb < 0) continue;             // uniform across block
    __syncthreads();                  // previous iteration readers done (also Q-frag reads)
    {
      const int row = tid >> 2;
      const int cg = (tid & 3) * 16;
      const ushort* sk = Kb + ((size_t)bh * 4096 + kb * 64 + row) * 64 + cg;
      short8 k0 = *(const short8*)sk;
      short8 k1 = *(const short8*)(sk + 8);
      const ushort* sv = Vt + ((size_t)bh * 64 + row) * 4096 + kb * 64 + cg;
      short8 v0 = *(const short8*)sv;
      short8 v1 = *(const short8*)(sv + 8);
      *(short8*)&Ks[row][cg]     = k0;
      *(short8*)&Ks[row][cg + 8] = k1;
      *(short8*)&Vs[row][cg]     = v0;
      *(short8*)&Vs[row][cg + 8] = v1;
    }
    __syncthreads();

    // S = Q * K^T  (Q pre-scaled)
    f32x4 s[4];
    #pragma unroll
    for (int ni = 0; ni < 4; ++ni) {
      f32x4 z = {};
      #pragma unroll
      for (int kc = 0; kc < 2; ++kc) {
        short8 kf = *(const short8*)&Ks[ni * 16 + c][kc * 32 + g * 8];
        z = MFMA16(qf[kc], kf, z);
      }
      s[ni] = z;
    }

    // ALiBi bias + online softmax (rows live in 16-lane groups)
    #pragma unroll
    for (int r = 0; r < 4; ++r) {
      const int qi = qb * 64 + i0 + g * 4 + r;
      float mx = -3e38f;
      #pragma unroll
      for (int ni = 0; ni < 4; ++ni) {
        const int kpos = kb * 64 + ni * 16 + c;
        const float dist = fabsf((float)(qi - kpos));
        const float val = s[ni][r] - slope * dist;
        s[ni][r] = val;
        mx = fmaxf(mx, val);
      }
      #pragma unroll
      for (int off = 1; off < 16; off <<= 1)
        mx = fmaxf(mx, __shfl_xor(mx, off, 16));
      const float mnew = fmaxf(mrun[r], mx);
      const float sf = __expf(mrun[r] - mnew);
      mrun[r] = mnew;
      float rsum = 0.f;
      #pragma unroll
      for (int ni = 0; ni < 4; ++ni) {
        const float p = __expf(s[ni][r] - mnew);
        s[ni][r] = p;
        rsum += p;
      }
      #pragma unroll
      for (int off = 1; off < 16; off <<= 1)
        rsum += __shfl_xor(rsum, off, 16);
      lrun[r] = lrun[r] * sf + rsum;
      #pragma unroll
      for (int di = 0; di < 4; ++di)
        accO[di][r] *= sf;
    }

    // P -> LDS (per-wave buffer), re-read as A-fragments
    #pragma unroll
    for (int ni = 0; ni < 4; ++ni)
      #pragma unroll
      for (int r = 0; r < 4; ++r)
        Ps[w][g * 4 + r][ni * 16 + c] = f2bf(s[ni][r]);

    short8 pf[2];
    pf[0] = *(const short8*)&Ps[w][c][g * 8];
    pf[1] = *(const short8*)&Ps[w][c][32 + g * 8];

    // O += P * V   (B-frag from Vt tile: lane reads Vt[d][j..j+7] contiguous)
    #pragma unroll
    for (int di = 0; di < 4; ++di) {
      #pragma unroll
      for (int jc = 0; jc < 2; ++jc) {
        short8 vf = *(const short8*)&Vs[di * 16 + c][jc * 32 + g * 8];
        accO[di] = MFMA16(pf[jc], vf, accO[di]);
      }
    }
  }

  // epilogue: O /= l, write to X2 [B*L][1024] at col h*64+d
  #pragma unroll
  for (int di = 0; di < 4; ++di) {
    #pragma unroll
    for (int r = 0; r < 4; ++r) {
      const float o = accO[di][r] / lrun[r];
      const int mrow = qb * 64 + i0 + g * 4 + r;
      X2[((size_t)b * 4096 + mrow) * 1024 + h * 64 + di * 16 + c] = f2bf(o);
    }
  }
}

// ---------------- GEMM2: output projection, f32 store ----------------
__global__ __launch_bounds__(256) void gemm_out(const ushort* __restrict__ X2,
                                                const ushort* __restrict__ W,
                                                float* __restrict__ out) {
  __shared__ ushort As[BM * BK];
  __shared__ ushort Bs[BN * BK];
  const int nbn = 1024 / BN;   // 8
  const int bm = blockIdx.x / nbn, bn = blockIdx.x % nbn;
  const int m0 = bm * BM, n0 = bn * BN;
  f32x4 acc[4][4] = {};
  gemm_tile(X2, W, 1024, m0, n0, As, Bs, acc);

  const int tid = threadIdx.x;
  const int w = tid >> 6, lane = tid & 63;
  const int g = lane >> 4, c = lane & 15;
  const int wr0 = (w >> 1) * 64, wc0 = (w & 1) * 64;
  #pragma unroll
  for (int mi = 0; mi < 4; ++mi) {
    #pragma unroll
    for (int ni = 0; ni < 4; ++ni) {
      const int n = n0 + wc0 + ni * 16 + c;
      #pragma unroll
      for (int r = 0; r < 4; ++r) {
        const int m = m0 + wr0 + mi * 16 + g * 4 + r;
        out[(size_t)m * 1024 + n] = acc[mi][ni][r];
      }
    }
  }
}

// ---------------- launch ----------------
extern "C" void kernel_launch(void* const* d_in, const int* in_sizes, int n_in,
                              void* d_out, int out_size, void* d_ws, size_t ws_size,
                              hipStream_t stream) {
  (void)in_sizes; (void)n_in; (void)out_size; (void)ws_size;
  const float* hs     = (const float*)d_in[0];
  const float* Wq     = (const float*)d_in[1];
  const float* Wk     = (const float*)d_in[2];
  const float* Wv     = (const float*)d_in[3];
  const float* Wo     = (const float*)d_in[4];
  const float* slopes = (const float*)d_in[5];
  const int*   bidx   = (const int*)d_in[6];
  float* out = (float*)d_out;

  char* ws = (char*)d_ws;
  // layout (bytes):                              size
  ushort* Xb   = (ushort*)(ws + 0);             // 16,777,216  (aliased by Vt later)
  ushort* Wqkv = (ushort*)(ws + 16777216);      //  6,291,456
  ushort* Wob  = (ushort*)(ws + 23068672);      //  2,097,152
  ushort* Qb   = (ushort*)(ws + 25165824);      // 16,777,216
  ushort* Kb   = (ushort*)(ws + 41943040);      // 16,777,216
  ushort* Vb   = (ushort*)(ws + 58720256);      // 16,777,216  (aliased by X2 later)
  ushort* Vt   = Xb;                            // Xb dead after gemm_qkv
  ushort* X2   = Vb;                            // Vb dead after transpose_v
  // total ws used: 75,497,472 bytes

  cvt_kernel<<<8192, 256, 0, stream>>>(hs, Xb, 2097152);
  cvt_kernel<<<1024, 256, 0, stream>>>(Wq, Wqkv,           262144);
  cvt_kernel<<<1024, 256, 0, stream>>>(Wk, Wqkv + 1048576, 262144);
  cvt_kernel<<<1024, 256, 0, stream>>>(Wv, Wqkv + 2097152, 262144);
  cvt_kernel<<<1024, 256, 0, stream>>>(Wo, Wob,            262144);

  gemm_qkv<<<64 * 24, 256, 0, stream>>>(Xb, Wqkv, Qb, Kb, Vb);
  transpose_v<<<2048, 256, 0, stream>>>(Vb, Vt);
  attn_kernel<<<2048, 256, 0, stream>>>(Qb, Kb, Vt, bidx, slopes, X2);
  gemm_out<<<64 * 8, 256, 0, stream>>>(X2, Wob, out);
}

// Round 2
// 194.334 us; speedup vs baseline: 1.1494x; 1.1494x over previous
//
#include <hip/hip_runtime.h>
#include <cstdint>
#include <cstddef>

// ---------------------------------------------------------------
// SparseAttention: B=2 L=4096 D=1024 H=16 HD=64 BS=64 NB=64 MAXB=11
// ---------------------------------------------------------------

#define MAXB 11

typedef __attribute__((ext_vector_type(8))) short short8;
typedef __attribute__((ext_vector_type(4))) float f32x4;

#define MFMA16(a, b, c) __builtin_amdgcn_mfma_f32_16x16x32_bf16((a), (b), (c), 0, 0, 0)

// Q pre-scaled by SCALE * log2(e) so softmax uses raw v_exp_f32 (exp2)
#define QSCALE 0.18033688011112042f   // 0.125 * 1.44269504089
#define LOG2E  1.44269504089f

__device__ __forceinline__ ushort f2bf(float f) {
  uint32_t u = __float_as_uint(f);
  u += 0x7FFFu + ((u >> 16) & 1u);   // RNE
  return (ushort)(u >> 16);
}

__device__ __forceinline__ uint32_t cvt_pk_bf16(float lo, float hi) {
  uint32_t r;
  asm("v_cvt_pk_bf16_f32 %0, %1, %2" : "=v"(r) : "v"(lo), "v"(hi));
  return r;
}

__device__ __forceinline__ void gload_lds16(const ushort* g, ushort* l) {
  __builtin_amdgcn_global_load_lds((const __attribute__((address_space(1))) void*)g,
                                   (__attribute__((address_space(3))) void*)l, 16, 0, 0);
}

// ---------------- f32 -> bf16 conversion (x4 vectorized) ----------------
__global__ __launch_bounds__(256) void cvt_kernel(const float* __restrict__ src,
                                                  ushort* __restrict__ dst, int n4) {
  int i = blockIdx.x * 256 + threadIdx.x;
  if (i >= n4) return;
  const float4 v = reinterpret_cast<const float4*>(src)[i];
  ushort4 o;
  o.x = f2bf(v.x); o.y = f2bf(v.y); o.z = f2bf(v.z); o.w = f2bf(v.w);
  reinterpret_cast<ushort4*>(dst)[i] = o;
}

// ---------------- shared GEMM mainloop: C = A * B^T ----------------
#define BM 128
#define BN 128
#define BK 64

__device__ __forceinline__ void gemm_tile(const ushort* __restrict__ A,
                                          const ushort* __restrict__ Bm,
                                          int K, int m0, int n0,
                                          ushort* As, ushort* Bs,
                                          f32x4 acc[4][4]) {
  const int tid  = threadIdx.x;
  const int w    = tid >> 6;
  const int lane = tid & 63;
  const int g    = lane >> 4;
  const int c    = lane & 15;
  const int wr0  = (w >> 1) * 64;
  const int wc0  = (w & 1) * 64;
  const int fbase = w * 1024 + lane * 16;

  for (int kt = 0; kt < K; kt += BK) {
    __syncthreads();
    #pragma unroll
    for (int q = 0; q < 4; ++q) {
      int fb  = q * 4096 + fbase;
      int row = fb >> 7;
      int col = (fb & 127) >> 1;
      gload_lds16(A  + (size_t)(m0 + row) * K + kt + col, As + q * 2048 + w * 512);
      gload_lds16(Bm + (size_t)(n0 + row) * K + kt + col, Bs + q * 2048 + w * 512);
    }
    __syncthreads();
    #pragma unroll
    for (int kc = 0; kc < 2; ++kc) {
      short8 af[4], bfr[4];
      const int kk = kc * 32 + g * 8;
      #pragma unroll
      for (int mi = 0; mi < 4; ++mi)
        af[mi] = *(const short8*)(As + (wr0 + mi * 16 + c) * 64 + kk);
      #pragma unroll
      for (int ni = 0; ni < 4; ++ni)
        bfr[ni] = *(const short8*)(Bs + (wc0 + ni * 16 + c) * 64 + kk);
      #pragma unroll
      for (int mi = 0; mi < 4; ++mi)
        #pragma unroll
        for (int ni = 0; ni < 4; ++ni)
          acc[mi][ni] = MFMA16(af[mi], bfr[ni], acc[mi][ni]);
    }
  }
}

// ---------------- GEMM1: QKV projection with scatter epilogue ----------------
__global__ __launch_bounds__(256) void gemm_qkv(const ushort* __restrict__ Xb,
                                                const ushort* __restrict__ W,
                                                ushort* __restrict__ Qb,
                                                ushort* __restrict__ Kb,
                                                ushort* __restrict__ Vb) {
  __shared__ __align__(16) ushort As[BM * BK];
  __shared__ __align__(16) ushort Bs[BN * BK];
  const int nbn = 3072 / BN;   // 24
  const int bm = blockIdx.x / nbn, bn = blockIdx.x % nbn;
  const int m0 = bm * BM, n0 = bn * BN;
  f32x4 acc[4][4] = {};
  gemm_tile(Xb, W, 1024, m0, n0, As, Bs, acc);

  const int tid = threadIdx.x;
  const int w = tid >> 6, lane = tid & 63;
  const int g = lane >> 4, c = lane & 15;
  const int wr0 = (w >> 1) * 64, wc0 = (w & 1) * 64;
  #pragma unroll
  for (int mi = 0; mi < 4; ++mi) {
    #pragma unroll
    for (int ni = 0; ni < 4; ++ni) {
      const int n = n0 + wc0 + ni * 16 + c;
      const int part = n >> 10;
      const int h = (n >> 6) & 15;
      const int hd = n & 63;
      #pragma unroll
      for (int r = 0; r < 4; ++r) {
        const int m = m0 + wr0 + mi * 16 + g * 4 + r;
        const int b = m >> 12;
        const int lp = m & 4095;
        const size_t off = ((size_t)((b << 4) + h) * 4096 + lp) * 64 + hd;
        const float v = acc[mi][ni][r];
        if (part == 0)      Qb[off] = f2bf(v * QSCALE);
        else if (part == 1) Kb[off] = f2bf(v);
        else                Vb[off] = f2bf(v);
      }
    }
  }
}

// ---------------- V transpose: [B,H,L,64] -> [B,H,64,L] ----------------
__global__ __launch_bounds__(256) void transpose_v(const ushort* __restrict__ V,
                                                   ushort* __restrict__ Vt) {
  __shared__ __align__(16) ushort t[64][72];
  const int bid = blockIdx.x;
  const int bh = bid >> 6;
  const int blk = bid & 63;
  const int tid = threadIdx.x;
  const int row = tid >> 2;
  const int cg = (tid & 3) * 16;
  const ushort* src = V + ((size_t)bh * 4096 + blk * 64 + row) * 64 + cg;
  *(short8*)&t[row][cg]     = *(const short8*)src;
  *(short8*)&t[row][cg + 8] = *(const short8*)(src + 8);
  __syncthreads();
  short8 o0, o1;
  #pragma unroll
  for (int i = 0; i < 8; ++i) {
    o0[i] = (short)t[cg + i][row];
    o1[i] = (short)t[cg + 8 + i][row];
  }
  ushort* dst = Vt + ((size_t)bh * 64 + row) * 4096 + blk * 64 + cg;
  *(short8*)dst       = o0;
  *(short8*)(dst + 8) = o1;
}

// ---------------- block-sparse flash attention (swapped QK^T) ----------------
// One block per (b,h,qb); 4 waves x 16 q-rows. S^T = mfma(K,Q): lane owns one
// q-row (col=c), 16 keys -> row-reduce = 2 shuffles. O^T = mfma(V^T, P^T).
__global__ __launch_bounds__(256) void attn_kernel(const ushort* __restrict__ Qb,
                                                   const ushort* __restrict__ Kb,
                                                   const ushort* __restrict__ Vt,
                                                   const int* __restrict__ bidx,
                                                   const float* __restrict__ slopes,
                                                   ushort* __restrict__ X2) {
  __shared__ __align__(16) ushort Ks[4096];     // [key][d] 64x64, chunk-swizzled
  __shared__ __align__(16) ushort Vs[4096];     // [d][key] 64x64, chunk-swizzled
  __shared__ __align__(16) ushort Ps[4][16][80];// per-wave P [qrow][key], pad 80

  const int phys = blockIdx.x;
  const int bid  = (phys & 7) * 256 + (phys >> 3);   // XCD swizzle (2048%8==0)
  const int qb = bid & 63;
  const int bh = bid >> 6;
  const int h  = bh & 15;
  const int b  = bh >> 4;
  const int tid = threadIdx.x;
  const int w = tid >> 6, lane = tid & 63;
  const int g = lane >> 4, c = lane & 15;
  const int i0 = w * 16;
  const float slope = slopes[h] * LOG2E;
  const int swz = c & 7;

  // Q fragments (B-operand) straight from global; Q pre-scaled by QSCALE
  const ushort* qptr = Qb + ((size_t)bh * 4096 + qb * 64 + i0 + c) * 64 + g * 8;
  const short8 qf0 = *(const short8*)qptr;
  const short8 qf1 = *(const short8*)(qptr + 32);

  f32x4 accO[4] = {};                 // O^T: lane(g,c) reg(di,r): O[q=c][d=di*16+g*4+r]
  float mrun = -3e38f, lrun = 0.f;
  const int qi = qb * 64 + i0 + c;

  for (int m = 0; m < MAXB; ++m) {
    const int kb = bidx[qb * MAXB + m];   // uniform
    if (kb < 0) continue;
    __syncthreads();                      // previous readers done
    #pragma unroll
    for (int j = 0; j < 2; ++j) {
      const int n = w * 128 + j * 64 + lane;        // 16B-chunk index
      const int row = n >> 3;
      const int sc = ((n & 7) ^ (row & 7)) * 8;     // swizzled source column
      gload_lds16(Kb + ((size_t)bh * 4096 + kb * 64 + row) * 64 + sc,
                  Ks + (w * 128 + j * 64) * 8);
      gload_lds16(Vt + ((size_t)bh * 64 + row) * 4096 + kb * 64 + sc,
                  Vs + (w * 128 + j * 64) * 8);
    }
    __syncthreads();                      // vmcnt(0) drain + all waves see tiles

    // S^T = K * Q^T : s[ni] lane(g,c) reg r = S[q=c][key = ni*16+g*4+r]
    f32x4 s[4];
    #pragma unroll
    for (int ni = 0; ni < 4; ++ni) {
      f32x4 z = {};
      const ushort* kr = Ks + (ni * 16 + c) * 64;
      z = MFMA16(*(const short8*)(kr + (g ^ swz) * 8), qf0, z);
      z = MFMA16(*(const short8*)(kr + ((4 + g) ^ swz) * 8), qf1, z);
      s[ni] = z;
    }

    // ALiBi + online softmax (all in exp2 domain)
    float mx = -3e38f;
    const int ib0 = qi - kb * 64 - g * 4;
    #pragma unroll
    for (int ni = 0; ni < 4; ++ni) {
      const float base = (float)(ib0 - ni * 16);
      #pragma unroll
      for (int r = 0; r < 4; ++r) {
        const float val = fmaf(-slope, fabsf(base - (float)r), s[ni][r]);
        s[ni][r] = val;
        mx = fmaxf(mx, val);
      }
    }
    mx = fmaxf(mx, __shfl_xor(mx, 16));
    mx = fmaxf(mx, __shfl_xor(mx, 32));
    const float mnew = fmaxf(mrun, mx);
    const float sf = __builtin_amdgcn_exp2f(mrun - mnew);
    mrun = mnew;
    float lsum = 0.f;
    #pragma unroll
    for (int ni = 0; ni < 4; ++ni)
      #pragma unroll
      for (int r = 0; r < 4; ++r) {
        const float pv = __builtin_amdgcn_exp2f(s[ni][r] - mnew);
        s[ni][r] = pv;
        lsum += pv;
      }
    lsum += __shfl_xor(lsum, 16);
    lsum += __shfl_xor(lsum, 32);
    lrun = lrun * sf + lsum;
    #pragma unroll
    for (int di = 0; di < 4; ++di)
      #pragma unroll
      for (int r = 0; r < 4; ++r)
        accO[di][r] *= sf;

    // pack P (bf16) into per-wave LDS [qrow][key]
    #pragma unroll
    for (int ni = 0; ni < 4; ++ni) {
      uint2 pk;
      pk.x = cvt_pk_bf16(s[ni][0], s[ni][1]);
      pk.y = cvt_pk_bf16(s[ni][2], s[ni][3]);
      *(uint2*)&Ps[w][c][ni * 16 + g * 4] = pk;
    }
    // cross-lane through LDS: enforce write->read order (rule #18)
    asm volatile("s_waitcnt lgkmcnt(0)" ::: "memory");
    __builtin_amdgcn_sched_barrier(0);
    const short8 pf0 = *(const short8*)&Ps[w][c][g * 8];
    const short8 pf1 = *(const short8*)&Ps[w][c][32 + g * 8];

    // O^T += V^T * P^T
    #pragma unroll
    for (int di = 0; di < 4; ++di) {
      const ushort* vr = Vs + (di * 16 + c) * 64;
      accO[di] = MFMA16(*(const short8*)(vr + (g ^ swz) * 8), pf0, accO[di]);
      accO[di] = MFMA16(*(const short8*)(vr + ((4 + g) ^ swz) * 8), pf1, accO[di]);
    }
  }

  // epilogue: O/l, pack 4 bf16 per 8B store
  const float rl = __builtin_amdgcn_rcpf(lrun);
  const size_t orow = (size_t)b * 4096 + qb * 64 + i0 + c;
  #pragma unroll
  for (int di = 0; di < 4; ++di) {
    uint2 pk;
    pk.x = cvt_pk_bf16(accO[di][0] * rl, accO[di][1] * rl);
    pk.y = cvt_pk_bf16(accO[di][2] * rl, accO[di][3] * rl);
    *(uint2*)&X2[orow * 1024 + h * 64 + di * 16 + g * 4] = pk;
  }
}

// ---------------- GEMM2: output projection, f32 store ----------------
__global__ __launch_bounds__(256) void gemm_out(const ushort* __restrict__ X2,
                                                const ushort* __restrict__ W,
                                                float* __restrict__ out) {
  __shared__ __align__(16) ushort As[BM * BK];
  __shared__ __align__(16) ushort Bs[BN * BK];
  const int nbn = 1024 / BN;   // 8
  const int bm = blockIdx.x / nbn, bn = blockIdx.x % nbn;
  const int m0 = bm * BM, n0 = bn * BN;
  f32x4 acc[4][4] = {};
  gemm_tile(X2, W, 1024, m0, n0, As, Bs, acc);

  const int tid = threadIdx.x;
  const int w = tid >> 6, lane = tid & 63;
  const int g = lane >> 4, c = lane & 15;
  const int wr0 = (w >> 1) * 64, wc0 = (w & 1) * 64;
  #pragma unroll
  for (int mi = 0; mi < 4; ++mi) {
    #pragma unroll
    for (int ni = 0; ni < 4; ++ni) {
      const int n = n0 + wc0 + ni * 16 + c;
      #pragma unroll
      for (int r = 0; r < 4; ++r) {
        const int m = m0 + wr0 + mi * 16 + g * 4 + r;
        out[(size_t)m * 1024 + n] = acc[mi][ni][r];
      }
    }
  }
}

// ---------------- launch ----------------
extern "C" void kernel_launch(void* const* d_in, const int* in_sizes, int n_in,
                              void* d_out, int out_size, void* d_ws, size_t ws_size,
                              hipStream_t stream) {
  (void)in_sizes; (void)n_in; (void)out_size; (void)ws_size;
  const float* hs     = (const float*)d_in[0];
  const float* Wq     = (const float*)d_in[1];
  const float* Wk     = (const float*)d_in[2];
  const float* Wv     = (const float*)d_in[3];
  const float* Wo     = (const float*)d_in[4];
  const float* slopes = (const float*)d_in[5];
  const int*   bidx   = (const int*)d_in[6];
  float* out = (float*)d_out;

  char* ws = (char*)d_ws;
  ushort* Xb   = (ushort*)(ws + 0);             // 16 MB (aliased by Vt later)
  ushort* Wqkv = (ushort*)(ws + 16777216);      //  6 MB
  ushort* Wob  = (ushort*)(ws + 23068672);      //  2 MB
  ushort* Qb   = (ushort*)(ws + 25165824);      // 16 MB
  ushort* Kb   = (ushort*)(ws + 41943040);      // 16 MB
  ushort* Vb   = (ushort*)(ws + 58720256);      // 16 MB (aliased by X2 later)
  ushort* Vt   = Xb;
  ushort* X2   = Vb;

  cvt_kernel<<<8192, 256, 0, stream>>>(hs, Xb, 2097152);
  cvt_kernel<<<1024, 256, 0, stream>>>(Wq, Wqkv,           262144);
  cvt_kernel<<<1024, 256, 0, stream>>>(Wk, Wqkv + 1048576, 262144);
  cvt_kernel<<<1024, 256, 0, stream>>>(Wv, Wqkv + 2097152, 262144);
  cvt_kernel<<<1024, 256, 0, stream>>>(Wo, Wob,            262144);

  gemm_qkv<<<64 * 24, 256, 0, stream>>>(Xb, Wqkv, Qb, Kb, Vb);
  transpose_v<<<2048, 256, 0, stream>>>(Vb, Vt);
  attn_kernel<<<2048, 256, 0, stream>>>(Qb, Kb, Vt, bidx, slopes, X2);
  gemm_out<<<64 * 8, 256, 0, stream>>>(X2, Wob, out);
}

// Round 3
// 172.042 us; speedup vs baseline: 1.2983x; 1.1296x over previous
//
#include <hip/hip_runtime.h>
#include <cstdint>
#include <cstddef>

// ---------------------------------------------------------------
// SparseAttention: B=2 L=4096 D=1024 H=16 HD=64 BS=64 NB=64 MAXB=11
// ---------------------------------------------------------------

#define MAXB 11
#define NT   16    // K-tiles: K=1024 / BK=64

typedef __attribute__((ext_vector_type(8))) short short8;
typedef __attribute__((ext_vector_type(4))) float f32x4;

#define MFMA16(a, b, c) __builtin_amdgcn_mfma_f32_16x16x32_bf16((a), (b), (c), 0, 0, 0)

#define QSCALE 0.18033688011112042f   // 0.125 * log2(e)
#define LOG2E  1.44269504089f

#define BAR()   asm volatile("s_barrier" ::: "memory")
#define LGKM0() asm volatile("s_waitcnt lgkmcnt(0)" ::: "memory")
#define VMC4()  asm volatile("s_waitcnt vmcnt(4)" ::: "memory")
#define VMC0()  asm volatile("s_waitcnt vmcnt(0)" ::: "memory")

__device__ __forceinline__ ushort f2bf(float f) {
  uint32_t u = __float_as_uint(f);
  u += 0x7FFFu + ((u >> 16) & 1u);   // RNE
  return (ushort)(u >> 16);
}

__device__ __forceinline__ uint32_t cvt_pk_bf16(float lo, float hi) {
  uint32_t r;
  asm("v_cvt_pk_bf16_f32 %0, %1, %2" : "=v"(r) : "v"(lo), "v"(hi));
  return r;
}

__device__ __forceinline__ void gload_lds16(const ushort* g, ushort* l) {
  __builtin_amdgcn_global_load_lds((const __attribute__((address_space(1))) void*)g,
                                   (__attribute__((address_space(3))) void*)l, 16, 0, 0);
}

// ---------------- f32 -> bf16 conversion ----------------
__global__ __launch_bounds__(256) void cvt_kernel(const float* __restrict__ src,
                                                  ushort* __restrict__ dst, int n4) {
  int i = blockIdx.x * 256 + threadIdx.x;
  if (i >= n4) return;
  const float4 v = reinterpret_cast<const float4*>(src)[i];
  ushort4 o;
  o.x = f2bf(v.x); o.y = f2bf(v.y); o.z = f2bf(v.z); o.w = f2bf(v.w);
  reinterpret_cast<ushort4*>(dst)[i] = o;
}

// ---------------- phase-pipelined GEMM mainloop: C = A * B^T ----------------
// BM=256, BN=128, BK=64, 512 threads = 8 waves (2M x 4N), wave tile 128x32.
// LDS 96KB: A dbuf 2x(2 halves of 128x64), B dbuf 2x(2 halves of 64x64),
// linear layout, XOR-swizzle applied on the global SOURCE address (m173).
// 3 phases per K-tile; counted vmcnt(4) at tile boundary (T4); setprio (T5).
#define AB_(buf,h) ((buf)*16384 + (h)*8192)         // A base, elems
#define BB_(buf,h) (32768 + (buf)*8192 + (h)*4096)  // B base, elems

__device__ __forceinline__ void gemm8_mainloop(const ushort* __restrict__ Ag,
                                               const ushort* __restrict__ Bg,
                                               int m0, int n0,
                                               ushort* smem, f32x4 acc[8][2]) {
  const int tid  = threadIdx.x;
  const int w    = tid >> 6;
  const int lane = tid & 63;
  const int g    = (lane >> 4) & 3;
  const int c    = lane & 15;
  const int wm   = w >> 2;           // 0..1
  const int wn   = w & 3;            // 0..3

  auto stageA = [&](int t, int h) {                  // 2 loads/thread (16KB half)
    const int buf = t & 1;
    #pragma unroll
    for (int i = 0; i < 2; ++i) {
      const int n  = i * 512 + w * 64 + lane;        // chunk 0..1023
      const int rh = n >> 3;
      const int j  = (n & 7) ^ (rh & 7);             // pre-swizzled source col
      gload_lds16(Ag + (size_t)(m0 + h * 128 + rh) * 1024 + t * 64 + j * 8,
                  smem + AB_(buf, h) + (i * 512 + w * 64) * 8);
    }
  };
  auto stageB = [&](int t, int h) {                  // 1 load/thread (8KB half)
    const int buf = t & 1;
    const int n  = w * 64 + lane;                    // chunk 0..511
    const int rh = n >> 3;
    const int j  = (n & 7) ^ (rh & 7);
    gload_lds16(Bg + (size_t)(n0 + h * 64 + rh) * 1024 + t * 64 + j * 8,
                smem + BB_(buf, h) + (w * 64) * 8);
  };
  auto rdA = [&](int buf, int mi, int kk) -> short8 {
    const int rh = mi * 16 + c;
    const int cc = (kk * 4 + g) ^ (rh & 7);
    return *(const short8*)(smem + AB_(buf, wm) + rh * 64 + cc * 8);
  };
  auto rdB = [&](int buf, int ni, int kk) -> short8 {
    const int nr = wn * 32 + ni * 16 + c;            // 0..127
    const int h  = nr >> 6, rh = nr & 63;
    const int cc = (kk * 4 + g) ^ (rh & 7);
    return *(const short8*)(smem + BB_(buf, h) + rh * 64 + cc * 8);
  };

  // prologue: A(0), B(0), A(1); wait for tile-0 only (A(1)'s 4 stay in flight)
  stageA(0, 0); stageA(0, 1);
  stageB(0, 0); stageB(0, 1);
  stageA(1, 0); stageA(1, 1);
  VMC4();
  BAR();

  short8 Alo[4][2], Ahi[4][2], Br[2][2];
  #pragma unroll 2
  for (int t = 0; t < NT; ++t) {
    const int buf = t & 1;
    // ---- phase 1: read A(lo) + all B, stage B-h0(t+1), MFMA lo x kk0 ----
    #pragma unroll
    for (int mi = 0; mi < 4; ++mi) {
      Alo[mi][0] = rdA(buf, mi, 0);
      Alo[mi][1] = rdA(buf, mi, 1);
    }
    #pragma unroll
    for (int ni = 0; ni < 2; ++ni) {
      Br[ni][0] = rdB(buf, ni, 0);
      Br[ni][1] = rdB(buf, ni, 1);
    }
    if (t + 1 < NT) stageB(t + 1, 0);
    LGKM0();
    __builtin_amdgcn_s_setprio(1);
    #pragma unroll
    for (int mi = 0; mi < 4; ++mi)
      #pragma unroll
      for (int ni = 0; ni < 2; ++ni)
        acc[mi][ni] = MFMA16(Alo[mi][0], Br[ni][0], acc[mi][ni]);
    __builtin_amdgcn_s_setprio(0);
    BAR();
    // ---- phase 2: read A(hi), stage B-h1(t+1), MFMA hi x kk0 ----
    #pragma unroll
    for (int mi = 0; mi < 4; ++mi) {
      Ahi[mi][0] = rdA(buf, mi + 4, 0);
      Ahi[mi][1] = rdA(buf, mi + 4, 1);
    }
    if (t + 1 < NT) stageB(t + 1, 1);
    LGKM0();
    __builtin_amdgcn_s_setprio(1);
    #pragma unroll
    for (int mi = 0; mi < 4; ++mi)
      #pragma unroll
      for (int ni = 0; ni < 2; ++ni)
        acc[mi + 4][ni] = MFMA16(Ahi[mi][0], Br[ni][0], acc[mi + 4][ni]);
    __builtin_amdgcn_s_setprio(0);
    BAR();   // all waves' A(t)-reads complete -> A region reusable
    // ---- phase 3: stage A(t+2), MFMA all x kk1, counted vmcnt ----
    if (t + 2 < NT) { stageA(t + 2, 0); stageA(t + 2, 1); }
    __builtin_amdgcn_s_setprio(1);
    #pragma unroll
    for (int mi = 0; mi < 4; ++mi)
      #pragma unroll
      for (int ni = 0; ni < 2; ++ni)
        acc[mi][ni] = MFMA16(Alo[mi][1], Br[ni][1], acc[mi][ni]);
    #pragma unroll
    for (int mi = 0; mi < 4; ++mi)
      #pragma unroll
      for (int ni = 0; ni < 2; ++ni)
        acc[mi + 4][ni] = MFMA16(Ahi[mi][1], Br[ni][1], acc[mi + 4][ni]);
    __builtin_amdgcn_s_setprio(0);
    if (t + 1 < NT) {
      if (t + 2 < NT) { VMC4(); } else { VMC0(); }   // A(t+2) stays in flight
    }
    BAR();
  }
}

// ---------------- GEMM1: QKV projection, scatter epilogue ----------------
__global__ __launch_bounds__(512, 2) void gemm_qkv(const ushort* __restrict__ Xb,
                                                   const ushort* __restrict__ W,
                                                   ushort* __restrict__ Qb,
                                                   ushort* __restrict__ Kb,
                                                   ushort* __restrict__ Vb) {
  __shared__ ushort smem[49152];   // 96 KB
  const int id  = blockIdx.x;                 // 768 blocks
  const int swz = (id & 7) * 96 + (id >> 3);  // XCD chunking (768%8==0)
  const int bm = swz / 24, bn = swz % 24;
  const int m0 = bm * 256, n0 = bn * 128;
  f32x4 acc[8][2] = {};
  gemm8_mainloop(Xb, W, m0, n0, smem, acc);

  const int tid = threadIdx.x;
  const int w = tid >> 6, lane = tid & 63;
  const int g = (lane >> 4) & 3, c = lane & 15;
  const int wm = w >> 2, wn = w & 3;
  #pragma unroll
  for (int mi = 0; mi < 8; ++mi) {
    #pragma unroll
    for (int ni = 0; ni < 2; ++ni) {
      const int n = n0 + wn * 32 + ni * 16 + c;
      const int part = n >> 10;
      const int h = (n >> 6) & 15;
      const int hd = n & 63;
      #pragma unroll
      for (int r = 0; r < 4; ++r) {
        const int m = m0 + wm * 128 + mi * 16 + g * 4 + r;
        const int b = m >> 12;
        const int lp = m & 4095;
        const size_t off = ((size_t)((b << 4) + h) * 4096 + lp) * 64 + hd;
        const float v = acc[mi][ni][r];
        if (part == 0)      Qb[off] = f2bf(v * QSCALE);
        else if (part == 1) Kb[off] = f2bf(v);
        else                Vb[off] = f2bf(v);
      }
    }
  }
}

// ---------------- GEMM2: output projection, f32 store ----------------
__global__ __launch_bounds__(512, 2) void gemm_out(const ushort* __restrict__ X2,
                                                   const ushort* __restrict__ W,
                                                   float* __restrict__ out) {
  __shared__ ushort smem[49152];
  const int id  = blockIdx.x;                 // 256 blocks
  const int swz = (id & 7) * 32 + (id >> 3);
  const int bm = swz / 8, bn = swz % 8;
  const int m0 = bm * 256, n0 = bn * 128;
  f32x4 acc[8][2] = {};
  gemm8_mainloop(X2, W, m0, n0, smem, acc);

  const int tid = threadIdx.x;
  const int w = tid >> 6, lane = tid & 63;
  const int g = (lane >> 4) & 3, c = lane & 15;
  const int wm = w >> 2, wn = w & 3;
  #pragma unroll
  for (int mi = 0; mi < 8; ++mi) {
    #pragma unroll
    for (int ni = 0; ni < 2; ++ni) {
      const int n = n0 + wn * 32 + ni * 16 + c;
      #pragma unroll
      for (int r = 0; r < 4; ++r) {
        const int m = m0 + wm * 128 + mi * 16 + g * 4 + r;
        out[(size_t)m * 1024 + n] = acc[mi][ni][r];
      }
    }
  }
}

// ---------------- V transpose: [B,H,L,64] -> [B,H,64,L] ----------------
__global__ __launch_bounds__(256) void transpose_v(const ushort* __restrict__ V,
                                                   ushort* __restrict__ Vt) {
  __shared__ __align__(16) ushort t[64][72];
  const int bid = blockIdx.x;
  const int bh = bid >> 6;
  const int blk = bid & 63;
  const int tid = threadIdx.x;
  const int row = tid >> 2;
  const int cg = (tid & 3) * 16;
  const ushort* src = V + ((size_t)bh * 4096 + blk * 64 + row) * 64 + cg;
  *(short8*)&t[row][cg]     = *(const short8*)src;
  *(short8*)&t[row][cg + 8] = *(const short8*)(src + 8);
  __syncthreads();
  short8 o0, o1;
  #pragma unroll
  for (int i = 0; i < 8; ++i) {
    o0[i] = (short)t[cg + i][row];
    o1[i] = (short)t[cg + 8 + i][row];
  }
  ushort* dst = Vt + ((size_t)bh * 64 + row) * 4096 + blk * 64 + cg;
  *(short8*)dst       = o0;
  *(short8*)(dst + 8) = o1;
}

// ---------------- block-sparse flash attention (swapped QK^T) ----------------
__global__ __launch_bounds__(256) void attn_kernel(const ushort* __restrict__ Qb,
                                                   const ushort* __restrict__ Kb,
                                                   const ushort* __restrict__ Vt,
                                                   const int* __restrict__ bidx,
                                                   const float* __restrict__ slopes,
                                                   ushort* __restrict__ X2) {
  __shared__ __align__(16) ushort Ks[4096];     // [key][d] 64x64, chunk-swizzled
  __shared__ __align__(16) ushort Vs[4096];     // [d][key] 64x64, chunk-swizzled
  __shared__ __align__(16) ushort Ps[4][16][80];

  const int phys = blockIdx.x;
  const int bid  = (phys & 7) * 256 + (phys >> 3);   // XCD swizzle
  const int qb = bid & 63;
  const int bh = bid >> 6;
  const int h  = bh & 15;
  const int b  = bh >> 4;
  const int tid = threadIdx.x;
  const int w = tid >> 6, lane = tid & 63;
  const int g = lane >> 4, c = lane & 15;
  const int i0 = w * 16;
  const float slope = slopes[h] * LOG2E;
  const int swz = c & 7;

  const ushort* qptr = Qb + ((size_t)bh * 4096 + qb * 64 + i0 + c) * 64 + g * 8;
  const short8 qf0 = *(const short8*)qptr;
  const short8 qf1 = *(const short8*)(qptr + 32);

  f32x4 accO[4] = {};
  float mrun = -3e38f, lrun = 0.f;
  const int qi = qb * 64 + i0 + c;

  for (int m = 0; m < MAXB; ++m) {
    const int kb = bidx[qb * MAXB + m];
    if (kb < 0) continue;
    __syncthreads();
    #pragma unroll
    for (int j = 0; j < 2; ++j) {
      const int n = w * 128 + j * 64 + lane;
      const int row = n >> 3;
      const int sc = ((n & 7) ^ (row & 7)) * 8;
      gload_lds16(Kb + ((size_t)bh * 4096 + kb * 64 + row) * 64 + sc,
                  Ks + (w * 128 + j * 64) * 8);
      gload_lds16(Vt + ((size_t)bh * 64 + row) * 4096 + kb * 64 + sc,
                  Vs + (w * 128 + j * 64) * 8);
    }
    __syncthreads();

    f32x4 s[4];
    #pragma unroll
    for (int ni = 0; ni < 4; ++ni) {
      f32x4 z = {};
      const ushort* kr = Ks + (ni * 16 + c) * 64;
      z = MFMA16(*(const short8*)(kr + (g ^ swz) * 8), qf0, z);
      z = MFMA16(*(const short8*)(kr + ((4 + g) ^ swz) * 8), qf1, z);
      s[ni] = z;
    }

    float mx = -3e38f;
    const int ib0 = qi - kb * 64 - g * 4;
    #pragma unroll
    for (int ni = 0; ni < 4; ++ni) {
      const float base = (float)(ib0 - ni * 16);
      #pragma unroll
      for (int r = 0; r < 4; ++r) {
        const float val = fmaf(-slope, fabsf(base - (float)r), s[ni][r]);
        s[ni][r] = val;
        mx = fmaxf(mx, val);
      }
    }
    mx = fmaxf(mx, __shfl_xor(mx, 16));
    mx = fmaxf(mx, __shfl_xor(mx, 32));
    const float mnew = fmaxf(mrun, mx);
    const float sf = __builtin_amdgcn_exp2f(mrun - mnew);
    mrun = mnew;
    float lsum = 0.f;
    #pragma unroll
    for (int ni = 0; ni < 4; ++ni)
      #pragma unroll
      for (int r = 0; r < 4; ++r) {
        const float pv = __builtin_amdgcn_exp2f(s[ni][r] - mnew);
        s[ni][r] = pv;
        lsum += pv;
      }
    lsum += __shfl_xor(lsum, 16);
    lsum += __shfl_xor(lsum, 32);
    lrun = lrun * sf + lsum;
    #pragma unroll
    for (int di = 0; di < 4; ++di)
      #pragma unroll
      for (int r = 0; r < 4; ++r)
        accO[di][r] *= sf;

    #pragma unroll
    for (int ni = 0; ni < 4; ++ni) {
      uint2 pk;
      pk.x = cvt_pk_bf16(s[ni][0], s[ni][1]);
      pk.y = cvt_pk_bf16(s[ni][2], s[ni][3]);
      *(uint2*)&Ps[w][c][ni * 16 + g * 4] = pk;
    }
    asm volatile("s_waitcnt lgkmcnt(0)" ::: "memory");
    __builtin_amdgcn_sched_barrier(0);
    const short8 pf0 = *(const short8*)&Ps[w][c][g * 8];
    const short8 pf1 = *(const short8*)&Ps[w][c][32 + g * 8];

    #pragma unroll
    for (int di = 0; di < 4; ++di) {
      const ushort* vr = Vs + (di * 16 + c) * 64;
      accO[di] = MFMA16(*(const short8*)(vr + (g ^ swz) * 8), pf0, accO[di]);
      accO[di] = MFMA16(*(const short8*)(vr + ((4 + g) ^ swz) * 8), pf1, accO[di]);
    }
  }

  const float rl = __builtin_amdgcn_rcpf(lrun);
  const size_t orow = (size_t)b * 4096 + qb * 64 + i0 + c;
  #pragma unroll
  for (int di = 0; di < 4; ++di) {
    uint2 pk;
    pk.x = cvt_pk_bf16(accO[di][0] * rl, accO[di][1] * rl);
    pk.y = cvt_pk_bf16(accO[di][2] * rl, accO[di][3] * rl);
    *(uint2*)&X2[orow * 1024 + h * 64 + di * 16 + g * 4] = pk;
  }
}

// ---------------- launch ----------------
extern "C" void kernel_launch(void* const* d_in, const int* in_sizes, int n_in,
                              void* d_out, int out_size, void* d_ws, size_t ws_size,
                              hipStream_t stream) {
  (void)in_sizes; (void)n_in; (void)out_size; (void)ws_size;
  const float* hs     = (const float*)d_in[0];
  const float* Wq     = (const float*)d_in[1];
  const float* Wk     = (const float*)d_in[2];
  const float* Wv     = (const float*)d_in[3];
  const float* Wo     = (const float*)d_in[4];
  const float* slopes = (const float*)d_in[5];
  const int*   bidx   = (const int*)d_in[6];
  float* out = (float*)d_out;

  char* ws = (char*)d_ws;
  ushort* Xb   = (ushort*)(ws + 0);             // 16 MB (aliased by Vt later)
  ushort* Wqkv = (ushort*)(ws + 16777216);      //  6 MB
  ushort* Wob  = (ushort*)(ws + 23068672);      //  2 MB
  ushort* Qb   = (ushort*)(ws + 25165824);      // 16 MB
  ushort* Kb   = (ushort*)(ws + 41943040);      // 16 MB
  ushort* Vb   = (ushort*)(ws + 58720256);      // 16 MB (aliased by X2 later)
  ushort* Vt   = Xb;
  ushort* X2   = Vb;

  cvt_kernel<<<8192, 256, 0, stream>>>(hs, Xb, 2097152);
  cvt_kernel<<<1024, 256, 0, stream>>>(Wq, Wqkv,           262144);
  cvt_kernel<<<1024, 256, 0, stream>>>(Wk, Wqkv + 1048576, 262144);
  cvt_kernel<<<1024, 256, 0, stream>>>(Wv, Wqkv + 2097152, 262144);
  cvt_kernel<<<1024, 256, 0, stream>>>(Wo, Wob,            262144);

  gemm_qkv<<<768, 512, 0, stream>>>(Xb, Wqkv, Qb, Kb, Vb);
  transpose_v<<<2048, 256, 0, stream>>>(Vb, Vt);
  attn_kernel<<<2048, 256, 0, stream>>>(Qb, Kb, Vt, bidx, slopes, X2);
  gemm_out<<<256, 512, 0, stream>>>(X2, Wob, out);
}